// Round 4
// baseline (188.503 us; speedup 1.0000x reference)
//
#include <hip/hip_runtime.h>
#include <math.h>

#define QN 128
#define SN 512
#define DN 768
#define TDN 1536
#define CN 64
#define KSPLIT 4
#define KCH 192   // 768 / KSPLIT

// ws layout (floats): hqp | hsp | aggbuf   (aggbuf zeroed by gemm)
#define HQP_ELEMS (KSPLIT * QN * TDN)
#define HSP_ELEMS (KSPLIT * SN * TDN)
#define ZERO_ELEMS (QN * CN)

// ---------------------------------------------------------------------------
// GEMM: out[m][n] = sum_k A[m][k] * W1[n][Koff+k], split-K 4.
// grid (12, 5, 4). block 256, micro 8x8, LDS [kk][m] transposed,
// double-buffered, register prefetch. (nt==0,kz==0) blocks also zero
// aggbuf, and one thread zeroes out[0] for finale's atomic loss sum.
// ---------------------------------------------------------------------------
__global__ __launch_bounds__(256) void gemm_kernel(
    const float* __restrict__ query, const float* __restrict__ support,
    const float* __restrict__ W1, float* __restrict__ hqp, float* __restrict__ hsp,
    float* __restrict__ zbuf, float* __restrict__ out)
{
    const int nt = blockIdx.x;   // 0..11
    const int mt = blockIdx.y;   // 0..4
    const int kz = blockIdx.z;   // 0..3
    const int tid = threadIdx.x;

    if (nt == 0 && kz == 0) {    // zero aggbuf (5 blocks x 256 thr x 8 floats)
        int o = (mt * 256 + tid) * 8;
        if (o < ZERO_ELEMS) {
            *(float4*)&zbuf[o]     = make_float4(0.f, 0.f, 0.f, 0.f);
            *(float4*)&zbuf[o + 4] = make_float4(0.f, 0.f, 0.f, 0.f);
        }
        if (mt == 0 && tid == 0) out[0] = 0.0f;
    }

    const float* A;
    float* Cout;
    int M0, Koff;
    if (mt == 0) { A = query;   M0 = 0;              Koff = 0;  Cout = hqp + (size_t)kz * QN * TDN; }
    else         { A = support; M0 = (mt - 1) * 128; Koff = DN; Cout = hsp + (size_t)kz * SN * TDN; }

    __shared__ float As[2][16][128];
    __shared__ float Bs[2][16][128];

    const int m   = tid >> 1;          // 0..127 staging row
    const int kkb = (tid & 1) * 8;     // k-half within 16-wide step

    const float* Aptr = &A [(size_t)(M0 + m) * DN  + kz * KCH + kkb];
    const float* Bptr = &W1[(size_t)(nt * 128 + m) * TDN + Koff + kz * KCH + kkb];

    float acc[8][8];
    #pragma unroll
    for (int i = 0; i < 8; ++i)
        #pragma unroll
        for (int j = 0; j < 8; ++j) acc[i][j] = 0.0f;

    {   // prologue: stage step 0
        float4 a0 = *(const float4*)(Aptr);
        float4 a1 = *(const float4*)(Aptr + 4);
        float4 b0 = *(const float4*)(Bptr);
        float4 b1 = *(const float4*)(Bptr + 4);
        As[0][kkb+0][m] = a0.x; As[0][kkb+1][m] = a0.y; As[0][kkb+2][m] = a0.z; As[0][kkb+3][m] = a0.w;
        As[0][kkb+4][m] = a1.x; As[0][kkb+5][m] = a1.y; As[0][kkb+6][m] = a1.z; As[0][kkb+7][m] = a1.w;
        Bs[0][kkb+0][m] = b0.x; Bs[0][kkb+1][m] = b0.y; Bs[0][kkb+2][m] = b0.z; Bs[0][kkb+3][m] = b0.w;
        Bs[0][kkb+4][m] = b1.x; Bs[0][kkb+5][m] = b1.y; Bs[0][kkb+6][m] = b1.z; Bs[0][kkb+7][m] = b1.w;
    }
    __syncthreads();

    const int tx = tid & 15;
    const int ty = tid >> 4;

    int buf = 0;
    for (int it = 0; it < 12; ++it) {
        float4 a0, a1, b0, b1;
        if (it < 11) {
            a0 = *(const float4*)(Aptr + (it + 1) * 16);
            a1 = *(const float4*)(Aptr + (it + 1) * 16 + 4);
            b0 = *(const float4*)(Bptr + (it + 1) * 16);
            b1 = *(const float4*)(Bptr + (it + 1) * 16 + 4);
        }
        #pragma unroll
        for (int kk = 0; kk < 16; ++kk) {
            float4 av0 = *(const float4*)&As[buf][kk][ty * 4];
            float4 av1 = *(const float4*)&As[buf][kk][64 + ty * 4];
            float4 bv0 = *(const float4*)&Bs[buf][kk][tx * 4];
            float4 bv1 = *(const float4*)&Bs[buf][kk][64 + tx * 4];
            float a[8] = {av0.x, av0.y, av0.z, av0.w, av1.x, av1.y, av1.z, av1.w};
            float b[8] = {bv0.x, bv0.y, bv0.z, bv0.w, bv1.x, bv1.y, bv1.z, bv1.w};
            #pragma unroll
            for (int i = 0; i < 8; ++i)
                #pragma unroll
                for (int j = 0; j < 8; ++j)
                    acc[i][j] += a[i] * b[j];
        }
        if (it < 11) {
            int nb = buf ^ 1;
            As[nb][kkb+0][m] = a0.x; As[nb][kkb+1][m] = a0.y; As[nb][kkb+2][m] = a0.z; As[nb][kkb+3][m] = a0.w;
            As[nb][kkb+4][m] = a1.x; As[nb][kkb+5][m] = a1.y; As[nb][kkb+6][m] = a1.z; As[nb][kkb+7][m] = a1.w;
            Bs[nb][kkb+0][m] = b0.x; Bs[nb][kkb+1][m] = b0.y; Bs[nb][kkb+2][m] = b0.z; Bs[nb][kkb+3][m] = b0.w;
            Bs[nb][kkb+4][m] = b1.x; Bs[nb][kkb+5][m] = b1.y; Bs[nb][kkb+6][m] = b1.z; Bs[nb][kkb+7][m] = b1.w;
            __syncthreads();
            buf = nb;
        }
    }

    #pragma unroll
    for (int i = 0; i < 8; ++i) {
        int row = M0 + ((i < 4) ? (ty * 4 + i) : (64 + ty * 4 + i - 4));
        float4 lo = make_float4(acc[i][0], acc[i][1], acc[i][2], acc[i][3]);
        float4 hi = make_float4(acc[i][4], acc[i][5], acc[i][6], acc[i][7]);
        *(float4*)&Cout[(size_t)row * TDN + nt * 128 + tx * 4]      = lo;
        *(float4*)&Cout[(size_t)row * TDN + nt * 128 + 64 + tx * 4] = hi;
    }
}

// ---------------------------------------------------------------------------
// Score + label-segmented reduce, fused. grid (16, 2, 8): jc (96 j), q-tile 64,
// s-tile 64. Stages hq/hs transposed (split-K partials summed, b1 folded into
// hq), 64x64 relu-dot tile (4x4 micro), spill to LDS, run-length label reduce,
// atomicAdd into aggbuf[q][c].
// ---------------------------------------------------------------------------
__global__ __launch_bounds__(256) void score_kernel(
    const float* __restrict__ hqp, const float* __restrict__ hsp,
    const float* __restrict__ b1, const float* __restrict__ W2,
    const int* __restrict__ labels, float* __restrict__ aggbuf)
{
    const int jc = blockIdx.x;   // 0..15
    const int qt = blockIdx.y;   // 0..1
    const int st = blockIdx.z;   // 0..7

    __shared__ float hqT[96][64];
    __shared__ float hsT[96][64];
    __shared__ float w2s[96];
    __shared__ float sc[64][68];
    __shared__ int   lab[64];

    const int tid = threadIdx.x;
    if (tid < 64) lab[tid] = labels[st * 64 + tid];

    #pragma unroll
    for (int l = 0; l < 6; ++l) {
        int idx  = tid + l * 256;         // 0..1535
        int row  = idx / 24;              // 0..63
        int quad = idx - row * 24;        // 0..23
        int j    = jc * 96 + quad * 4;
        float4 hv = *(const float4*)&b1[j];
        float4 sv = make_float4(0.f, 0.f, 0.f, 0.f);
        #pragma unroll
        for (int p = 0; p < KSPLIT; ++p) {
            float4 h = *(const float4*)&hqp[(size_t)p * QN * TDN + (size_t)(qt * 64 + row) * TDN + j];
            float4 g = *(const float4*)&hsp[(size_t)p * SN * TDN + (size_t)(st * 64 + row) * TDN + j];
            hv.x += h.x; hv.y += h.y; hv.z += h.z; hv.w += h.w;
            sv.x += g.x; sv.y += g.y; sv.z += g.z; sv.w += g.w;
        }
        hqT[quad*4+0][row] = hv.x; hqT[quad*4+1][row] = hv.y;
        hqT[quad*4+2][row] = hv.z; hqT[quad*4+3][row] = hv.w;
        hsT[quad*4+0][row] = sv.x; hsT[quad*4+1][row] = sv.y;
        hsT[quad*4+2][row] = sv.z; hsT[quad*4+3][row] = sv.w;
    }
    if (tid < 24) {
        float4 w = *(const float4*)&W2[jc * 96 + tid * 4];
        w2s[tid*4+0] = w.x; w2s[tid*4+1] = w.y;
        w2s[tid*4+2] = w.z; w2s[tid*4+3] = w.w;
    }
    __syncthreads();

    const int tx = tid & 15;
    const int ty = tid >> 4;
    float acc[4][4];
    #pragma unroll
    for (int i = 0; i < 4; ++i)
        #pragma unroll
        for (int j = 0; j < 4; ++j) acc[i][j] = 0.0f;

    #pragma unroll 4
    for (int jj = 0; jj < 96; ++jj) {
        float4 a4 = *(const float4*)&hqT[jj][ty * 4];
        float4 b4 = *(const float4*)&hsT[jj][tx * 4];
        float w = w2s[jj];
        float a[4] = {a4.x, a4.y, a4.z, a4.w};
        float b[4] = {b4.x, b4.y, b4.z, b4.w};
        #pragma unroll
        for (int i = 0; i < 4; ++i)
            #pragma unroll
            for (int j = 0; j < 4; ++j)
                acc[i][j] += w * fmaxf(a[i] + b[j], 0.0f);
    }

    #pragma unroll
    for (int i = 0; i < 4; ++i)
        *(float4*)&sc[ty * 4 + i][tx * 4] =
            make_float4(acc[i][0], acc[i][1], acc[i][2], acc[i][3]);
    __syncthreads();

    {   // run-length label reduce: thread = (q-row, 16-wide s segment)
        int row = tid >> 2;
        int seg = tid & 3;
        float* aggrow = aggbuf + (size_t)(qt * 64 + row) * CN;
        int   runc = lab[seg * 16];
        float runv = 0.0f;
        #pragma unroll
        for (int k = 0; k < 16; ++k) {
            int s = seg * 16 + k;
            int c = lab[s];
            if (c != runc) { atomicAdd(&aggrow[runc], runv); runv = 0.0f; runc = c; }
            runv += sc[row][s];
        }
        atomicAdd(&aggrow[runc], runv);
    }
}

// ---------------------------------------------------------------------------
// Finale: grid 32 x 256 — one wave per query. Histogram counts in LDS, then
// per-wave: mean, fused max+argmax, exp-sum, pred flag; lane0 atomicAdds
// -logp/QN into out[0] (zeroed by gemm).
// ---------------------------------------------------------------------------
__global__ __launch_bounds__(256) void finale_kernel(
    const float* __restrict__ aggbuf, const int* __restrict__ labels,
    const int* __restrict__ tgt, float* __restrict__ out)
{
    __shared__ float cnt[CN];
    const int tid = threadIdx.x;
    if (tid < CN) cnt[tid] = 0.0f;
    __syncthreads();
    atomicAdd(&cnt[labels[tid]],       1.0f);
    atomicAdd(&cnt[labels[tid + 256]], 1.0f);
    __syncthreads();

    const int lane = tid & 63;
    const int q    = blockIdx.x * 4 + (tid >> 6);

    float v = aggbuf[(size_t)q * CN + lane] / fmaxf(cnt[lane], 1.0f);
    float av = v; int am = lane;
    #pragma unroll
    for (int off = 1; off < 64; off <<= 1) {
        float ov = __shfl_xor(av, off);
        int   oi = __shfl_xor(am, off);
        if (ov > av || (ov == av && oi < am)) { av = ov; am = oi; }
    }
    float m = av;
    float e = expf(v - m);
    #pragma unroll
    for (int off = 1; off < 64; off <<= 1)
        e += __shfl_xor(e, off);
    int t = tgt[q];
    float vt = __shfl(v, t, 64);
    if (lane == 0) {
        out[1 + q] = (am == t) ? 1.0f : 0.0f;
        atomicAdd(&out[0], -(vt - m - logf(e)) / (float)QN);
    }
}

extern "C" void kernel_launch(void* const* d_in, const int* in_sizes, int n_in,
                              void* d_out, int out_size, void* d_ws, size_t ws_size,
                              hipStream_t stream) {
    const float* query   = (const float*)d_in[0];
    const float* support = (const float*)d_in[1];
    const float* W1      = (const float*)d_in[2];
    const float* b1      = (const float*)d_in[3];
    const float* W2      = (const float*)d_in[4];
    // d_in[5] = b2: uniform shift, cancels under log_softmax/argmax -> unused
    const int* labels = (const int*)d_in[6];
    const int* tgt    = (const int*)d_in[7];

    float* ws     = (float*)d_ws;
    float* hqp    = ws;                    // KSPLIT*QN*TDN
    float* hsp    = hqp + HQP_ELEMS;       // KSPLIT*SN*TDN
    float* aggbuf = hsp + HSP_ELEMS;       // QN*CN  (zeroed by gemm)
    float* out    = (float*)d_out;

    // Pipeline launched TWICE (idempotent: gemm re-zeroes aggbuf + out[0]).
    // Calibration: dur_R4 - dur_R3 ~= cost of one full kernel pipeline,
    // separating controllable kernel time from fixed harness overhead.
    #pragma unroll
    for (int rep = 0; rep < 2; ++rep) {
        hipLaunchKernelGGL(gemm_kernel, dim3(12, 5, 4), dim3(256), 0, stream,
                           query, support, W1, hqp, hsp, aggbuf, out);
        hipLaunchKernelGGL(score_kernel, dim3(16, 2, 8), dim3(256), 0, stream,
                           hqp, hsp, b1, W2, labels, aggbuf);
        hipLaunchKernelGGL(finale_kernel, dim3(32), dim3(256), 0, stream,
                           aggbuf, labels, tgt, out);
    }
}

// Round 5
// 118.994 us; speedup vs baseline: 1.5841x; 1.5841x over previous
//
#include <hip/hip_runtime.h>
#include <math.h>

#define QN 128
#define SN 512
#define DN 768
#define TDN 1536
#define CN 64
#define KSPLIT 4
#define KCH 192   // 768 / KSPLIT

#define HQP_ELEMS (KSPLIT * QN * TDN)
#define HSP_ELEMS (KSPLIT * SN * TDN)
#define ZERO_ELEMS (QN * CN)

typedef short short8 __attribute__((ext_vector_type(8)));
typedef float f32x4 __attribute__((ext_vector_type(4)));

#define LDS_STRIDE 40            // 32 k + 8 pad (bf16 units) -> 2-way bank alias only
#define PLANE (128 * LDS_STRIDE) // shorts per plane

__device__ __forceinline__ short bf16_rtn(float x) {
    unsigned u = __float_as_uint(x);
    return (short)((u + 0x7fffu + ((u >> 16) & 1u)) >> 16);
}
__device__ __forceinline__ float bf16_tof(short s) {
    return __uint_as_float(((unsigned)(unsigned short)s) << 16);
}

// ---------------------------------------------------------------------------
// bf16x3 MFMA GEMM: out[m][n] = sum_k A[m][k]*W1[n][Koff+k], split-K 4.
// grid (12, 5, 4) = 240 blocks; block 256 = 4 waves, each wave a 64x64
// quadrant of the 128x128 tile as 4x4 subtiles of 16x16x32 MFMA.
// A,B split hi/lo bf16 at LDS-staging; 3 MFMAs (hh, hl, lh) per pair give
// ~2^-18 relative error. LDS planes [m][k] padded to stride 40.
// (nt==0,kz==0) blocks also zero aggbuf; one thread zeroes out[0].
// ---------------------------------------------------------------------------
__global__ __launch_bounds__(256) void gemm_kernel(
    const float* __restrict__ query, const float* __restrict__ support,
    const float* __restrict__ W1, float* __restrict__ hqp, float* __restrict__ hsp,
    float* __restrict__ zbuf, float* __restrict__ out)
{
    const int nt = blockIdx.x;   // 0..11
    const int mt = blockIdx.y;   // 0..4
    const int kz = blockIdx.z;   // 0..3
    const int tid = threadIdx.x;

    if (nt == 0 && kz == 0) {    // zero aggbuf (5 blocks x 256 thr x 8 floats)
        int o = (mt * 256 + tid) * 8;
        if (o < ZERO_ELEMS) {
            *(float4*)&zbuf[o]     = make_float4(0.f, 0.f, 0.f, 0.f);
            *(float4*)&zbuf[o + 4] = make_float4(0.f, 0.f, 0.f, 0.f);
        }
        if (mt == 0 && tid == 0) out[0] = 0.0f;
    }

    const float* A;
    float* Cout;
    int M0, Koff;
    if (mt == 0) { A = query;   M0 = 0;              Koff = 0;  Cout = hqp + (size_t)kz * QN * TDN; }
    else         { A = support; M0 = (mt - 1) * 128; Koff = DN; Cout = hsp + (size_t)kz * SN * TDN; }

    // planes: [buf][Ah, Al, Bh, Bl]
    __shared__ short lds[2][4][PLANE];

    const int r  = tid >> 1;         // staging row 0..127
    const int kh = (tid & 1) * 16;   // k-offset 0 or 16

    const float* Arow = &A [(size_t)(M0 + r) * DN  + kz * KCH + kh];
    const float* Brow = &W1[(size_t)(nt * 128 + r) * TDN + Koff + kz * KCH + kh];

    f32x4 acc[4][4];
    #pragma unroll
    for (int i = 0; i < 4; ++i)
        #pragma unroll
        for (int j = 0; j < 4; ++j)
            acc[i][j] = (f32x4){0.f, 0.f, 0.f, 0.f};

    // staging converter: 4 float4 (16 floats) -> hi/lo short8 pairs into plane
    auto stage = [&](short* plane, float4 v0, float4 v1, float4 v2, float4 v3) {
        float f[16] = {v0.x,v0.y,v0.z,v0.w, v1.x,v1.y,v1.z,v1.w,
                       v2.x,v2.y,v2.z,v2.w, v3.x,v3.y,v3.z,v3.w};
        short hi[16], lo[16];
        #pragma unroll
        for (int i = 0; i < 16; ++i) {
            hi[i] = bf16_rtn(f[i]);
            lo[i] = bf16_rtn(f[i] - bf16_tof(hi[i]));
        }
        short* dsth = plane + r * LDS_STRIDE + kh;
        #pragma unroll
        for (int i = 0; i < 16; ++i) dsth[i] = hi[i];
        short* dstl = plane + PLANE + r * LDS_STRIDE + kh;   // Al = Ah+PLANE, Bl = Bh+PLANE
        #pragma unroll
        for (int i = 0; i < 16; ++i) dstl[i] = lo[i];
    };

    {   // prologue: stage step 0 into buf 0
        float4 a0 = *(const float4*)(Arow),     a1 = *(const float4*)(Arow + 4);
        float4 a2 = *(const float4*)(Arow + 8), a3 = *(const float4*)(Arow + 12);
        float4 b0 = *(const float4*)(Brow),     b1 = *(const float4*)(Brow + 4);
        float4 b2 = *(const float4*)(Brow + 8), b3 = *(const float4*)(Brow + 12);
        stage(lds[0][0], a0, a1, a2, a3);   // writes Ah + Al
        stage(lds[0][2], b0, b1, b2, b3);   // writes Bh + Bl
    }
    __syncthreads();

    const int lane  = tid & 63;
    const int w     = tid >> 6;
    const int lm    = lane & 15;
    const int quad  = lane >> 4;
    const int wrow0 = (w >> 1) * 64;
    const int wcol0 = (w & 1) * 64;

    int buf = 0;
    for (int step = 0; step < 6; ++step) {
        float4 a0, a1, a2, a3, b0, b1, b2, b3;
        if (step < 5) {
            const float* An = Arow + (step + 1) * 32;
            const float* Bn = Brow + (step + 1) * 32;
            a0 = *(const float4*)(An);     a1 = *(const float4*)(An + 4);
            a2 = *(const float4*)(An + 8); a3 = *(const float4*)(An + 12);
            b0 = *(const float4*)(Bn);     b1 = *(const float4*)(Bn + 4);
            b2 = *(const float4*)(Bn + 8); b3 = *(const float4*)(Bn + 12);
        }

        const short* Ah = lds[buf][0];
        const short* Al = lds[buf][1];
        const short* Bh = lds[buf][2];
        const short* Bl = lds[buf][3];

        short8 ah[4], al[4], bh[4], bl[4];
        #pragma unroll
        for (int mi = 0; mi < 4; ++mi) {
            int off = (wrow0 + mi * 16 + lm) * LDS_STRIDE + quad * 8;
            ah[mi] = *(const short8*)&Ah[off];
            al[mi] = *(const short8*)&Al[off];
        }
        #pragma unroll
        for (int ni = 0; ni < 4; ++ni) {
            int off = (wcol0 + ni * 16 + lm) * LDS_STRIDE + quad * 8;
            bh[ni] = *(const short8*)&Bh[off];
            bl[ni] = *(const short8*)&Bl[off];
        }
        #pragma unroll
        for (int mi = 0; mi < 4; ++mi)
            #pragma unroll
            for (int ni = 0; ni < 4; ++ni) {
                acc[mi][ni] = __builtin_amdgcn_mfma_f32_16x16x32_bf16(ah[mi], bh[ni], acc[mi][ni], 0, 0, 0);
                acc[mi][ni] = __builtin_amdgcn_mfma_f32_16x16x32_bf16(ah[mi], bl[ni], acc[mi][ni], 0, 0, 0);
                acc[mi][ni] = __builtin_amdgcn_mfma_f32_16x16x32_bf16(al[mi], bh[ni], acc[mi][ni], 0, 0, 0);
            }

        if (step < 5) {
            int nb = buf ^ 1;
            stage(lds[nb][0], a0, a1, a2, a3);
            stage(lds[nb][2], b0, b1, b2, b3);
            __syncthreads();
            buf = nb;
        }
    }

    // epilogue: C/D layout col=lane&15, row=quad*4+reg (HW-verified m89/m91)
    #pragma unroll
    for (int mi = 0; mi < 4; ++mi)
        #pragma unroll
        for (int ni = 0; ni < 4; ++ni) {
            int grow = M0 + wrow0 + mi * 16 + quad * 4;
            int gcol = nt * 128 + wcol0 + ni * 16 + lm;
            #pragma unroll
            for (int rr = 0; rr < 4; ++rr)
                Cout[(size_t)(grow + rr) * TDN + gcol] = acc[mi][ni][rr];
        }
}

// ---------------------------------------------------------------------------
// Score + label-segmented reduce, fused. grid (16, 2, 8): jc (96 j), q-tile 64,
// s-tile 64. Stages hq/hs transposed (split-K partials summed, b1 folded into
// hq), 64x64 relu-dot tile (4x4 micro), spill to LDS, run-length label reduce,
// atomicAdd into aggbuf[q][c].
// ---------------------------------------------------------------------------
__global__ __launch_bounds__(256) void score_kernel(
    const float* __restrict__ hqp, const float* __restrict__ hsp,
    const float* __restrict__ b1, const float* __restrict__ W2,
    const int* __restrict__ labels, float* __restrict__ aggbuf)
{
    const int jc = blockIdx.x;   // 0..15
    const int qt = blockIdx.y;   // 0..1
    const int st = blockIdx.z;   // 0..7

    __shared__ float hqT[96][64];
    __shared__ float hsT[96][64];
    __shared__ float w2s[96];
    __shared__ float sc[64][68];
    __shared__ int   lab[64];

    const int tid = threadIdx.x;
    if (tid < 64) lab[tid] = labels[st * 64 + tid];

    #pragma unroll
    for (int l = 0; l < 6; ++l) {
        int idx  = tid + l * 256;         // 0..1535
        int row  = idx / 24;              // 0..63
        int quad = idx - row * 24;        // 0..23
        int j    = jc * 96 + quad * 4;
        float4 hv = *(const float4*)&b1[j];
        float4 sv = make_float4(0.f, 0.f, 0.f, 0.f);
        #pragma unroll
        for (int p = 0; p < KSPLIT; ++p) {
            float4 h = *(const float4*)&hqp[(size_t)p * QN * TDN + (size_t)(qt * 64 + row) * TDN + j];
            float4 g = *(const float4*)&hsp[(size_t)p * SN * TDN + (size_t)(st * 64 + row) * TDN + j];
            hv.x += h.x; hv.y += h.y; hv.z += h.z; hv.w += h.w;
            sv.x += g.x; sv.y += g.y; sv.z += g.z; sv.w += g.w;
        }
        hqT[quad*4+0][row] = hv.x; hqT[quad*4+1][row] = hv.y;
        hqT[quad*4+2][row] = hv.z; hqT[quad*4+3][row] = hv.w;
        hsT[quad*4+0][row] = sv.x; hsT[quad*4+1][row] = sv.y;
        hsT[quad*4+2][row] = sv.z; hsT[quad*4+3][row] = sv.w;
    }
    if (tid < 24) {
        float4 w = *(const float4*)&W2[jc * 96 + tid * 4];
        w2s[tid*4+0] = w.x; w2s[tid*4+1] = w.y;
        w2s[tid*4+2] = w.z; w2s[tid*4+3] = w.w;
    }
    __syncthreads();

    const int tx = tid & 15;
    const int ty = tid >> 4;
    float acc[4][4];
    #pragma unroll
    for (int i = 0; i < 4; ++i)
        #pragma unroll
        for (int j = 0; j < 4; ++j) acc[i][j] = 0.0f;

    #pragma unroll 4
    for (int jj = 0; jj < 96; ++jj) {
        float4 a4 = *(const float4*)&hqT[jj][ty * 4];
        float4 b4 = *(const float4*)&hsT[jj][tx * 4];
        float w = w2s[jj];
        float a[4] = {a4.x, a4.y, a4.z, a4.w};
        float b[4] = {b4.x, b4.y, b4.z, b4.w};
        #pragma unroll
        for (int i = 0; i < 4; ++i)
            #pragma unroll
            for (int j = 0; j < 4; ++j)
                acc[i][j] += w * fmaxf(a[i] + b[j], 0.0f);
    }

    #pragma unroll
    for (int i = 0; i < 4; ++i)
        *(float4*)&sc[ty * 4 + i][tx * 4] =
            make_float4(acc[i][0], acc[i][1], acc[i][2], acc[i][3]);
    __syncthreads();

    {   // run-length label reduce: thread = (q-row, 16-wide s segment)
        int row = tid >> 2;
        int seg = tid & 3;
        float* aggrow = aggbuf + (size_t)(qt * 64 + row) * CN;
        int   runc = lab[seg * 16];
        float runv = 0.0f;
        #pragma unroll
        for (int k = 0; k < 16; ++k) {
            int s = seg * 16 + k;
            int c = lab[s];
            if (c != runc) { atomicAdd(&aggrow[runc], runv); runv = 0.0f; runc = c; }
            runv += sc[row][s];
        }
        atomicAdd(&aggrow[runc], runv);
    }
}

// ---------------------------------------------------------------------------
// Finale: grid 32 x 256 — one wave per query. Histogram counts in LDS, then
// per-wave: mean, fused max+argmax, exp-sum, pred flag; lane0 atomicAdds
// -logp/QN into out[0] (zeroed by gemm).
// ---------------------------------------------------------------------------
__global__ __launch_bounds__(256) void finale_kernel(
    const float* __restrict__ aggbuf, const int* __restrict__ labels,
    const int* __restrict__ tgt, float* __restrict__ out)
{
    __shared__ float cnt[CN];
    const int tid = threadIdx.x;
    if (tid < CN) cnt[tid] = 0.0f;
    __syncthreads();
    atomicAdd(&cnt[labels[tid]],       1.0f);
    atomicAdd(&cnt[labels[tid + 256]], 1.0f);
    __syncthreads();

    const int lane = tid & 63;
    const int q    = blockIdx.x * 4 + (tid >> 6);

    float v = aggbuf[(size_t)q * CN + lane] / fmaxf(cnt[lane], 1.0f);
    float av = v; int am = lane;
    #pragma unroll
    for (int off = 1; off < 64; off <<= 1) {
        float ov = __shfl_xor(av, off);
        int   oi = __shfl_xor(am, off);
        if (ov > av || (ov == av && oi < am)) { av = ov; am = oi; }
    }
    float m = av;
    float e = expf(v - m);
    #pragma unroll
    for (int off = 1; off < 64; off <<= 1)
        e += __shfl_xor(e, off);
    int t = tgt[q];
    float vt = __shfl(v, t, 64);
    if (lane == 0) {
        out[1 + q] = (am == t) ? 1.0f : 0.0f;
        atomicAdd(&out[0], -(vt - m - logf(e)) / (float)QN);
    }
}

extern "C" void kernel_launch(void* const* d_in, const int* in_sizes, int n_in,
                              void* d_out, int out_size, void* d_ws, size_t ws_size,
                              hipStream_t stream) {
    const float* query   = (const float*)d_in[0];
    const float* support = (const float*)d_in[1];
    const float* W1      = (const float*)d_in[2];
    const float* b1      = (const float*)d_in[3];
    const float* W2      = (const float*)d_in[4];
    // d_in[5] = b2: uniform shift, cancels under log_softmax/argmax -> unused
    const int* labels = (const int*)d_in[6];
    const int* tgt    = (const int*)d_in[7];

    float* ws     = (float*)d_ws;
    float* hqp    = ws;                    // KSPLIT*QN*TDN
    float* hsp    = hqp + HQP_ELEMS;       // KSPLIT*SN*TDN
    float* aggbuf = hsp + HSP_ELEMS;       // QN*CN  (zeroed by gemm)
    float* out    = (float*)d_out;

    hipLaunchKernelGGL(gemm_kernel, dim3(12, 5, 4), dim3(256), 0, stream,
                       query, support, W1, hqp, hsp, aggbuf, out);
    hipLaunchKernelGGL(score_kernel, dim3(16, 2, 8), dim3(256), 0, stream,
                       hqp, hsp, b1, W2, labels, aggbuf);
    hipLaunchKernelGGL(finale_kernel, dim3(32), dim3(256), 0, stream,
                       aggbuf, labels, tgt, out);
}